// Round 10
// baseline (272.586 us; speedup 1.0000x reference)
//
#include <hip/hip_runtime.h>
#include <math.h>

typedef __attribute__((ext_vector_type(8))) short short8;
typedef __attribute__((ext_vector_type(4))) float float4v;

__device__ __forceinline__ unsigned short f2bf(float f) {
    unsigned int u = __builtin_bit_cast(unsigned int, f);
    u += 0x7fffu + ((u >> 16) & 1u);
    return (unsigned short)(u >> 16);
}
__device__ __forceinline__ float bf2f(unsigned short h) {
    unsigned int u = ((unsigned int)h) << 16;
    return __builtin_bit_cast(float, u);
}

#define KCH 16

// ---------- prologue: zero barriers | castW1 | castW2 | tr_fc | prep_cand ----------
__global__ __launch_bounds__(256) void prologue_kernel(
    const float* __restrict__ W1, const float* __restrict__ W2,
    unsigned short* __restrict__ W1h, unsigned short* __restrict__ W2h,
    const float* __restrict__ fc, unsigned short* __restrict__ fcT,
    const float* __restrict__ xyzc, float4* __restrict__ cand4,
    unsigned* __restrict__ bar,
    int M, int Cc, int nW1, int nW2, int nTR, int Mb) {
    __shared__ float t[64][65];
    int b = blockIdx.x, tid = threadIdx.x;
    if (b == 0 && tid < 8) bar[tid] = 0;   // reset grid-barrier counters each launch
    if (b < nW1) {
        int q = b * 256 + tid;
        float4 v = ((const float4*)W1)[q];
        ushort4 o; o.x = f2bf(v.x); o.y = f2bf(v.y); o.z = f2bf(v.z); o.w = f2bf(v.w);
        ((ushort4*)W1h)[q] = o;
    } else if (b < nW1 + nW2) {
        int q = (b - nW1) * 256 + tid;
        float4 v = ((const float4*)W2)[q];
        ushort4 o; o.x = f2bf(v.x); o.y = f2bf(v.y); o.z = f2bf(v.z); o.w = f2bf(v.w);
        ((ushort4*)W2h)[q] = o;
    } else if (b < nW1 + nW2 + nTR) {
        int b2 = b - nW1 - nW2;
        int jb = b2 % Mb, cb = b2 / Mb;
        int j0 = jb * 64, c0 = cb * 64;
        int tx = tid & 63, ty = tid >> 6;
#pragma unroll
        for (int i = 0; i < 16; ++i)
            t[ty + 4 * i][tx] = fc[(size_t)(c0 + ty + 4 * i) * M + j0 + tx];
        __syncthreads();
#pragma unroll
        for (int i = 0; i < 16; ++i)
            fcT[(size_t)(j0 + ty + 4 * i) * Cc + c0 + tx] = f2bf(t[tx][ty + 4 * i]);
    } else {
        int j = (b - nW1 - nW2 - nTR) * 256 + tid;
        if (j < M) {
            float cx = xyzc[j], cy = xyzc[M + j], cz = xyzc[2 * M + j];
            float cc = __fadd_rn(__fadd_rn(__fmul_rn(cx, cx), __fmul_rn(cy, cy)), __fmul_rn(cz, cz));
            cand4[j] = make_float4(cx, cy, cz, cc);
        }
    }
}

// ---------- kNN pass 1 ----------
__global__ __launch_bounds__(256) void knn_scan_kernel(
    const float* __restrict__ xyzf, const float4* __restrict__ cand4,
    int N, int M, float* __restrict__ candd, int* __restrict__ candi) {
    int n = blockIdx.x * 256 + threadIdx.x;
    int ch = blockIdx.y;
    float qx = xyzf[n], qy = xyzf[N + n], qz = xyzf[2 * N + n];
    float qq = __fadd_rn(__fadd_rn(__fmul_rn(qx, qx), __fmul_rn(qy, qy)), __fmul_rn(qz, qz));
    int cs = M / KCH;
    int j0 = ch * cs;
    float d0 = INFINITY, d1 = INFINITY, d2 = INFINITY;
    int i0 = 0x7fffffff, i1 = 0x7fffffff, i2 = 0x7fffffff;
#pragma unroll 8
    for (int jj = 0; jj < cs; ++jj) {
        int j = j0 + jj;
        float4 c = cand4[j];
        float s  = fmaf(qz, c.z, fmaf(qy, c.y, __fmul_rn(qx, c.x)));
        float dd = __fadd_rn(__fsub_rn(qq, 2.f * s), c.w);
        if (dd < d2) {
            if (dd < d1) {
                d2 = d1; i2 = i1;
                if (dd < d0) { d1 = d0; i1 = i0; d0 = dd; i0 = j; }
                else         { d1 = dd; i1 = j; }
            } else { d2 = dd; i2 = j; }
        }
    }
    size_t base = (size_t)(ch * 3) * N + n;
    candd[base] = d0; candd[base + N] = d1; candd[base + 2 * (size_t)N] = d2;
    candi[base] = i0; candi[base + N] = i1; candi[base + 2 * (size_t)N] = i2;
}

// ---------- kNN pass 2 ----------
__global__ __launch_bounds__(256) void knn_merge_kernel(
    const float* __restrict__ candd, const int* __restrict__ candi,
    const float* __restrict__ xyzf, const float* __restrict__ xyzc,
    int N, int M, int* __restrict__ idx3, float* __restrict__ w3) {
    int n = blockIdx.x * 256 + threadIdx.x;
    float bd0 = INFINITY, bd1 = INFINITY, bd2 = INFINITY;
    int bi0 = 0x7fffffff, bi1 = 0x7fffffff, bi2 = 0x7fffffff;
#pragma unroll
    for (int g = 0; g < (KCH * 3) / 8; ++g) {
        float dd[8]; int ii[8];
#pragma unroll
        for (int e = 0; e < 8; ++e) {
            size_t off = (size_t)(g * 8 + e) * N + n;
            dd[e] = candd[off];
            ii[e] = candi[off];
        }
#pragma unroll
        for (int e = 0; e < 8; ++e) {
            float d = dd[e]; int i = ii[e];
            if (d < bd2 || (d == bd2 && i < bi2)) {
                if (d < bd1 || (d == bd1 && i < bi1)) {
                    bd2 = bd1; bi2 = bi1;
                    if (d < bd0 || (d == bd0 && i < bi0)) { bd1 = bd0; bi1 = bi0; bd0 = d; bi0 = i; }
                    else                                  { bd1 = d; bi1 = i; }
                } else { bd2 = d; bi2 = i; }
            }
        }
    }
    float qx = xyzf[n], qy = xyzf[N + n], qz = xyzf[2 * N + n];
    int iif[3] = {bi0, bi1, bi2};
    float u[3];
#pragma unroll
    for (int s = 0; s < 3; ++s) {
        int i = iif[s];
        float cx = xyzc[i], cy = xyzc[M + i], cz = xyzc[2 * M + i];
        float dx = __fsub_rn(qx, cx), dy = __fsub_rn(qy, cy), dz = __fsub_rn(qz, cz);
        float dd = __fadd_rn(__fadd_rn(__fmul_rn(dx, dx), __fmul_rn(dy, dy)), __fmul_rn(dz, dz));
        float dist = fmaxf(sqrtf(dd), 1e-8f);
        u[s] = 1.f / dist;
    }
    float su = __fadd_rn(__fadd_rn(u[0], u[1]), u[2]);
#pragma unroll
    for (int s = 0; s < 3; ++s) {
        idx3[n * 3 + s] = iif[s];
        w3[n * 3 + s] = u[s] / su;
    }
}

// ---------- build x: interp | tr_ff ----------
__global__ __launch_bounds__(256) void build_x_kernel(
    const unsigned short* __restrict__ fcT, const int* __restrict__ idx3,
    const float* __restrict__ w3, const float* __restrict__ ff,
    unsigned short* __restrict__ xbuf,
    int N, int Cin, int Cc, int nInterp, int cxB, int Nb) {
    __shared__ float t[64][65];
    int b = blockIdx.x, tid = threadIdx.x;
    if (b < nInterp) {
        int cx = b % cxB, n = b / cxB;
        int c = cx * 256 + tid;
        int i0 = idx3[n * 3], i1 = idx3[n * 3 + 1], i2 = idx3[n * 3 + 2];
        float w0 = w3[n * 3], w1 = w3[n * 3 + 1], w2 = w3[n * 3 + 2];
        float f0 = bf2f(fcT[(size_t)i0 * Cc + c]);
        float f1 = bf2f(fcT[(size_t)i1 * Cc + c]);
        float f2_ = bf2f(fcT[(size_t)i2 * Cc + c]);
        float v = fmaf(w2, f2_, fmaf(w1, f1, w0 * f0));
        xbuf[(size_t)n * Cin + c] = f2bf(v);
    } else {
        int b2 = b - nInterp;
        int nb = b2 % Nb, cb = b2 / Nb;
        int n0 = nb * 64, c0 = cb * 64;
        int tx = tid & 63, ty = tid >> 6;
#pragma unroll
        for (int i = 0; i < 16; ++i)
            t[ty + 4 * i][tx] = ff[(size_t)(c0 + ty + 4 * i) * N + n0 + tx];
        __syncthreads();
#pragma unroll
        for (int i = 0; i < 16; ++i)
            xbuf[(size_t)(n0 + ty + 4 * i) * Cin + Cc + c0 + tx] = f2bf(t[tx][ty + 4 * i]);
    }
}

// ---------- grid barrier (cooperative, own counters; bounded spin) ----------
__device__ __forceinline__ void grid_bar(unsigned* cnt, unsigned tgt) {
    __syncthreads();
    if (threadIdx.x == 0) {
        __threadfence();  // device-scope release of this block's writes
        __hip_atomic_fetch_add(cnt, 1u, __ATOMIC_ACQ_REL, __HIP_MEMORY_SCOPE_AGENT);
        for (unsigned it = 0; it < 10000000u; ++it) {
            if (__hip_atomic_load(cnt, __ATOMIC_ACQUIRE, __HIP_MEMORY_SCOPE_AGENT) >= tgt) break;
            __builtin_amdgcn_s_sleep(8);
        }
    }
    __syncthreads();
}

// ---------- one GEMM phase: acc = A(128 rows) x B(128 rows)^T over K; + channel partials ----------
__device__ __forceinline__ void gemm_phase(
    const unsigned short* __restrict__ A, const unsigned short* __restrict__ B,
    int K, int O, int o0, int n0, short* As, short* Bs,
    int tid, int wm, int wn, int r16, int kg,
    float4v acc[4][4], float* __restrict__ psumG, float* __restrict__ psqG, int nb) {
#pragma unroll
    for (int a = 0; a < 4; ++a)
#pragma unroll
        for (int b = 0; b < 4; ++b)
            acc[a][b] = (float4v){0.f, 0.f, 0.f, 0.f};
    for (int k0 = 0; k0 < K; k0 += 32) {
#pragma unroll
        for (int h = 0; h < 2; ++h) {
            int ch = tid + h * 256;
            int row = ch >> 2, kq = ch & 3;
            __builtin_amdgcn_global_load_lds(
                (const __attribute__((address_space(1))) void*)(A + (size_t)(o0 + row) * K + k0 + kq * 8),
                (__attribute__((address_space(3))) void*)&As[ch * 8], 16, 0, 0);
            __builtin_amdgcn_global_load_lds(
                (const __attribute__((address_space(1))) void*)(B + (size_t)(n0 + row) * K + k0 + kq * 8),
                (__attribute__((address_space(3))) void*)&Bs[ch * 8], 16, 0, 0);
        }
        __syncthreads();
        short8 af[4], bfr[4];
#pragma unroll
        for (int mi = 0; mi < 4; ++mi)
            af[mi] = *(const short8*)(const void*)&As[(wm * 64 + mi * 16 + r16) * 32 + kg * 8];
#pragma unroll
        for (int ni = 0; ni < 4; ++ni)
            bfr[ni] = *(const short8*)(const void*)&Bs[(wn * 64 + ni * 16 + r16) * 32 + kg * 8];
#pragma unroll
        for (int mi = 0; mi < 4; ++mi)
#pragma unroll
            for (int ni = 0; ni < 4; ++ni)
                acc[mi][ni] = __builtin_amdgcn_mfma_f32_16x16x32_bf16(af[mi], bfr[ni], acc[mi][ni], 0, 0, 0);
        __syncthreads();
    }
    // per-channel (sum, sumsq) partials over this block's 128 cols
    float2* red = (float2*)As;
#pragma unroll
    for (int mi = 0; mi < 4; ++mi) {
#pragma unroll
        for (int r = 0; r < 4; ++r) {
            float s = 0.f, q = 0.f;
#pragma unroll
            for (int ni = 0; ni < 4; ++ni) {
                float v = acc[mi][ni][r];
                s += v; q += v * v;
            }
#pragma unroll
            for (int off = 1; off <= 8; off <<= 1) {
                s += __shfl_xor(s, off);
                q += __shfl_xor(q, off);
            }
            if (r16 == 0) {
                int row = wm * 64 + mi * 16 + kg * 4 + r;
                red[row * 2 + wn] = make_float2(s, q);
            }
        }
    }
    __syncthreads();
    if (tid < 128) {
        float2 a = red[tid * 2 + 0], b = red[tid * 2 + 1];
        psumG[(size_t)nb * O + o0 + tid] = a.x + b.x;
        psqG [(size_t)nb * O + o0 + tid] = a.y + b.y;
    }
}

// ---------- cooperative MLP mega-kernel: gemm1 | bn1+relu+tr | gemm2 | bn2+relu ----------
__global__ __launch_bounds__(256, 2) void mlp_mega_kernel(
    const unsigned short* __restrict__ W1h, const unsigned short* __restrict__ W2h,
    const unsigned short* __restrict__ xbuf, unsigned short* __restrict__ y2,
    float* __restrict__ out, float* __restrict__ psumG, float* __restrict__ psqG,
    const float* __restrict__ g1, const float* __restrict__ b1,
    const float* __restrict__ g2, const float* __restrict__ b2,
    int N, int K1, int h, unsigned* __restrict__ bar) {
    __shared__ short As[128 * 32], Bs[128 * 32];
    __shared__ float2 msr[128], gbl[128];
    int tid = threadIdx.x;
    int lane = tid & 63, wid = tid >> 6;
    int wm = wid & 1, wn = wid >> 1;
    int r16 = lane & 15, kg = lane >> 4;
    int NBn = N / 128;
    int nb = blockIdx.x % NBn, ob = blockIdx.x / NBn;
    int o0 = ob * 128, n0 = nb * 128;
    unsigned tgt = (unsigned)gridDim.x;
    float4v acc[4][4];

    // phase A: GEMM1 (K = Cin)
    gemm_phase(W1h, xbuf, K1, h, o0, n0, As, Bs, tid, wm, wn, r16, kg, acc, psumG, psqG, nb);
    grid_bar(&bar[0], tgt);

    // phase B: stats reduce + BN1 + ReLU + transposed bf16 write to y2[N][h]
    if (tid < 128) {
        int o = o0 + tid;
        float s = 0.f, q = 0.f;
#pragma unroll 8
        for (int i = 0; i < NBn; ++i) { s += psumG[(size_t)i * h + o]; q += psqG[(size_t)i * h + o]; }
        float m = s / N;
        msr[tid] = make_float2(m, rsqrtf(q / N - m * m + 1e-5f));
        gbl[tid] = make_float2(g1[o], b1[o]);
    }
    __syncthreads();
#pragma unroll
    for (int mi = 0; mi < 4; ++mi) {
        int obl = wm * 64 + mi * 16 + kg * 4;
#pragma unroll
        for (int ni = 0; ni < 4; ++ni) {
            int n = n0 + wn * 64 + ni * 16 + r16;
            ushort4 pk;
#pragma unroll
            for (int r = 0; r < 4; ++r) {
                float2 ms = msr[obl + r], gb = gbl[obl + r];
                float v = gb.x * (acc[mi][ni][r] - ms.x) * ms.y + gb.y;
                ((unsigned short*)&pk)[r] = f2bf(fmaxf(v, 0.f));
            }
            *(ushort4*)(void*)&y2[(size_t)n * h + o0 + obl] = pk;
        }
    }
    grid_bar(&bar[1], tgt);

    // phase C: GEMM2 (K = h, B = y2)
    gemm_phase(W2h, y2, h, h, o0, n0, As, Bs, tid, wm, wn, r16, kg, acc, psumG, psqG, nb);
    grid_bar(&bar[2], tgt);

    // phase D: stats reduce + BN2 + ReLU + final f32 write to out[h][N]
    if (tid < 128) {
        int o = o0 + tid;
        float s = 0.f, q = 0.f;
#pragma unroll 8
        for (int i = 0; i < NBn; ++i) { s += psumG[(size_t)i * h + o]; q += psqG[(size_t)i * h + o]; }
        float m = s / N;
        msr[tid] = make_float2(m, rsqrtf(q / N - m * m + 1e-5f));
        gbl[tid] = make_float2(g2[o], b2[o]);
    }
    __syncthreads();
#pragma unroll
    for (int mi = 0; mi < 4; ++mi) {
        int obl = wm * 64 + mi * 16 + kg * 4;
#pragma unroll
        for (int r = 0; r < 4; ++r) {
            float2 ms = msr[obl + r], gb = gbl[obl + r];
            int o = o0 + obl + r;
#pragma unroll
            for (int ni = 0; ni < 4; ++ni) {
                int col = n0 + wn * 64 + ni * 16 + r16;
                float v = gb.x * (acc[mi][ni][r] - ms.x) * ms.y + gb.y;
                out[(size_t)o * N + col] = fmaxf(v, 0.f);
            }
        }
    }
}

extern "C" void kernel_launch(void* const* d_in, const int* in_sizes, int n_in,
                              void* d_out, int out_size, void* d_ws, size_t ws_size,
                              hipStream_t stream) {
    const float* xyzf = (const float*)d_in[0];
    const float* xyzc = (const float*)d_in[1];
    const float* ff   = (const float*)d_in[2];
    const float* fc   = (const float*)d_in[3];
    const float* W1   = (const float*)d_in[4];
    const float* g1   = (const float*)d_in[5];
    const float* b1   = (const float*)d_in[6];
    const float* W2   = (const float*)d_in[7];
    const float* g2   = (const float*)d_in[8];
    const float* b2   = (const float*)d_in[9];

    int N  = in_sizes[0] / 3;       // 16384
    int M  = in_sizes[1] / 3;       // 4096
    int Cf = in_sizes[2] / N;       // 256
    int Cc = in_sizes[3] / M;       // 512
    int h1 = in_sizes[5];           // 512
    int Cin = Cc + Cf;              // 768
    float* out = (float*)d_out;

    // workspace carve (~48 MB)
    char* p = (char*)d_ws;
    unsigned short* W1h = (unsigned short*)p; p += (size_t)h1 * Cin * 2;
    unsigned short* W2h = (unsigned short*)p; p += (size_t)h1 * h1 * 2;
    unsigned short* fcT = (unsigned short*)p; p += (size_t)M * Cc * 2;
    int*   idx3 = (int*)p;   p += (size_t)N * 3 * sizeof(int);
    float* w3   = (float*)p; p += (size_t)N * 3 * sizeof(float);
    float4* cand4 = (float4*)p; p += (size_t)M * sizeof(float4);
    int NBn = N / 128;
    float* psumG = (float*)p; p += (size_t)NBn * h1 * sizeof(float);
    float* psqG  = (float*)p; p += (size_t)NBn * h1 * sizeof(float);
    unsigned* bar = (unsigned*)p; p += 64;   // 8 counters, padded
    unsigned short* y2 = (unsigned short*)p; p += (size_t)N * h1 * 2;
    unsigned short* xbuf = (unsigned short*)p; p += (size_t)N * Cin * 2;
    // aliases inside xbuf (dead before xbuf is first written):
    float* candd = (float*)xbuf;                        // [KCH*3][N]
    int*   candi = (int*)((char*)xbuf + (size_t)KCH * 3 * N * sizeof(float));

    // 1. prologue (also zeroes barrier counters each launch/replay)
    int nW1 = h1 * Cin / 1024, nW2 = h1 * h1 / 1024;
    int Mb = M / 64, nTR = Mb * (Cc / 64), nPR = (M + 255) / 256;
    prologue_kernel<<<nW1 + nW2 + nTR + nPR, 256, 0, stream>>>(
        W1, W2, W1h, W2h, fc, fcT, xyzc, cand4, bar, M, Cc, nW1, nW2, nTR, Mb);

    // 2-3. kNN
    knn_scan_kernel<<<dim3(N / 256, KCH), 256, 0, stream>>>(xyzf, cand4, N, M, candd, candi);
    knn_merge_kernel<<<N / 256, 256, 0, stream>>>(candd, candi, xyzf, xyzc, N, M, idx3, w3);

    // 4. build x
    int cxB = Cc / 256, nInterp = cxB * N, Nb = N / 64, nTF = Nb * (Cf / 64);
    build_x_kernel<<<nInterp + nTF, 256, 0, stream>>>(
        fcT, idx3, w3, ff, xbuf, N, Cin, Cc, nInterp, cxB, Nb);

    // 5. cooperative MLP mega-kernel (512 blocks = (N/128) x (h1/128), 2 blocks/CU)
    {
        dim3 grid(NBn * (h1 / 128)), block(256);
        void* ka[] = {
            (void*)&W1h, (void*)&W2h, (void*)&xbuf, (void*)&y2, (void*)&out,
            (void*)&psumG, (void*)&psqG,
            (void*)&g1, (void*)&b1, (void*)&g2, (void*)&b2,
            (void*)&N, (void*)&Cin, (void*)&h1, (void*)&bar
        };
        hipLaunchCooperativeKernel((const void*)mlp_mega_kernel, grid, block, ka, 0, stream);
    }
}

// Round 11
// 162.173 us; speedup vs baseline: 1.6808x; 1.6808x over previous
//
#include <hip/hip_runtime.h>
#include <math.h>

typedef __attribute__((ext_vector_type(8))) short short8;
typedef __attribute__((ext_vector_type(4))) float float4v;

__device__ __forceinline__ unsigned short f2bf(float f) {
    unsigned int u = __builtin_bit_cast(unsigned int, f);
    u += 0x7fffu + ((u >> 16) & 1u);
    return (unsigned short)(u >> 16);
}
__device__ __forceinline__ float bf2f(unsigned short h) {
    unsigned int u = ((unsigned int)h) << 16;
    return __builtin_bit_cast(float, u);
}

#define KCH 16

// ---------- prologue: castW1 | castW2 | tr_fc | prep_cand ----------
__global__ __launch_bounds__(256) void prologue_kernel(
    const float* __restrict__ W1, const float* __restrict__ W2,
    unsigned short* __restrict__ W1h, unsigned short* __restrict__ W2h,
    const float* __restrict__ fc, unsigned short* __restrict__ fcT,
    const float* __restrict__ xyzc, float4* __restrict__ cand4,
    int M, int Cc, int nW1, int nW2, int nTR, int Mb) {
    __shared__ float t[64][65];
    int b = blockIdx.x, tid = threadIdx.x;
    if (b < nW1) {
        int q = b * 256 + tid;
        float4 v = ((const float4*)W1)[q];
        ushort4 o; o.x = f2bf(v.x); o.y = f2bf(v.y); o.z = f2bf(v.z); o.w = f2bf(v.w);
        ((ushort4*)W1h)[q] = o;
    } else if (b < nW1 + nW2) {
        int q = (b - nW1) * 256 + tid;
        float4 v = ((const float4*)W2)[q];
        ushort4 o; o.x = f2bf(v.x); o.y = f2bf(v.y); o.z = f2bf(v.z); o.w = f2bf(v.w);
        ((ushort4*)W2h)[q] = o;
    } else if (b < nW1 + nW2 + nTR) {
        int b2 = b - nW1 - nW2;
        int jb = b2 % Mb, cb = b2 / Mb;
        int j0 = jb * 64, c0 = cb * 64;
        int tx = tid & 63, ty = tid >> 6;
#pragma unroll
        for (int i = 0; i < 16; ++i)
            t[ty + 4 * i][tx] = fc[(size_t)(c0 + ty + 4 * i) * M + j0 + tx];
        __syncthreads();
#pragma unroll
        for (int i = 0; i < 16; ++i)
            fcT[(size_t)(j0 + ty + 4 * i) * Cc + c0 + tx] = f2bf(t[tx][ty + 4 * i]);
    } else {
        int j = (b - nW1 - nW2 - nTR) * 256 + tid;
        if (j < M) {
            float cx = xyzc[j], cy = xyzc[M + j], cz = xyzc[2 * M + j];
            float cc = __fadd_rn(__fadd_rn(__fmul_rn(cx, cx), __fmul_rn(cy, cy)), __fmul_rn(cz, cz));
            cand4[j] = make_float4(cx, cy, cz, cc);
        }
    }
}

// ---------- kNN pass 1 ----------
__global__ __launch_bounds__(256) void knn_scan_kernel(
    const float* __restrict__ xyzf, const float4* __restrict__ cand4,
    int N, int M, float* __restrict__ candd, int* __restrict__ candi) {
    int n = blockIdx.x * 256 + threadIdx.x;
    int ch = blockIdx.y;
    float qx = xyzf[n], qy = xyzf[N + n], qz = xyzf[2 * N + n];
    float qq = __fadd_rn(__fadd_rn(__fmul_rn(qx, qx), __fmul_rn(qy, qy)), __fmul_rn(qz, qz));
    int cs = M / KCH;
    int j0 = ch * cs;
    float d0 = INFINITY, d1 = INFINITY, d2 = INFINITY;
    int i0 = 0x7fffffff, i1 = 0x7fffffff, i2 = 0x7fffffff;
#pragma unroll 8
    for (int jj = 0; jj < cs; ++jj) {
        int j = j0 + jj;
        float4 c = cand4[j];
        float s  = fmaf(qz, c.z, fmaf(qy, c.y, __fmul_rn(qx, c.x)));
        float dd = __fadd_rn(__fsub_rn(qq, 2.f * s), c.w);
        if (dd < d2) {
            if (dd < d1) {
                d2 = d1; i2 = i1;
                if (dd < d0) { d1 = d0; i1 = i0; d0 = dd; i0 = j; }
                else         { d1 = dd; i1 = j; }
            } else { d2 = dd; i2 = j; }
        }
    }
    size_t base = (size_t)(ch * 3) * N + n;
    candd[base] = d0; candd[base + N] = d1; candd[base + 2 * (size_t)N] = d2;
    candi[base] = i0; candi[base + N] = i1; candi[base + 2 * (size_t)N] = i2;
}

// ---------- kNN pass 2 ----------
__global__ __launch_bounds__(256) void knn_merge_kernel(
    const float* __restrict__ candd, const int* __restrict__ candi,
    const float* __restrict__ xyzf, const float* __restrict__ xyzc,
    int N, int M, int* __restrict__ idx3, float* __restrict__ w3) {
    int n = blockIdx.x * 256 + threadIdx.x;
    float bd0 = INFINITY, bd1 = INFINITY, bd2 = INFINITY;
    int bi0 = 0x7fffffff, bi1 = 0x7fffffff, bi2 = 0x7fffffff;
#pragma unroll
    for (int g = 0; g < (KCH * 3) / 8; ++g) {
        float dd[8]; int ii[8];
#pragma unroll
        for (int e = 0; e < 8; ++e) {
            size_t off = (size_t)(g * 8 + e) * N + n;
            dd[e] = candd[off];
            ii[e] = candi[off];
        }
#pragma unroll
        for (int e = 0; e < 8; ++e) {
            float d = dd[e]; int i = ii[e];
            if (d < bd2 || (d == bd2 && i < bi2)) {
                if (d < bd1 || (d == bd1 && i < bi1)) {
                    bd2 = bd1; bi2 = bi1;
                    if (d < bd0 || (d == bd0 && i < bi0)) { bd1 = bd0; bi1 = bi0; bd0 = d; bi0 = i; }
                    else                                  { bd1 = d; bi1 = i; }
                } else { bd2 = d; bi2 = i; }
            }
        }
    }
    float qx = xyzf[n], qy = xyzf[N + n], qz = xyzf[2 * N + n];
    int iif[3] = {bi0, bi1, bi2};
    float u[3];
#pragma unroll
    for (int s = 0; s < 3; ++s) {
        int i = iif[s];
        float cx = xyzc[i], cy = xyzc[M + i], cz = xyzc[2 * M + i];
        float dx = __fsub_rn(qx, cx), dy = __fsub_rn(qy, cy), dz = __fsub_rn(qz, cz);
        float dd = __fadd_rn(__fadd_rn(__fmul_rn(dx, dx), __fmul_rn(dy, dy)), __fmul_rn(dz, dz));
        float dist = fmaxf(sqrtf(dd), 1e-8f);
        u[s] = 1.f / dist;
    }
    float su = __fadd_rn(__fadd_rn(u[0], u[1]), u[2]);
#pragma unroll
    for (int s = 0; s < 3; ++s) {
        idx3[n * 3 + s] = iif[s];
        w3[n * 3 + s] = u[s] / su;
    }
}

// ---------- build x: interp | tr_ff ----------
__global__ __launch_bounds__(256) void build_x_kernel(
    const unsigned short* __restrict__ fcT, const int* __restrict__ idx3,
    const float* __restrict__ w3, const float* __restrict__ ff,
    unsigned short* __restrict__ xbuf,
    int N, int Cin, int Cc, int nInterp, int cxB, int Nb) {
    __shared__ float t[64][65];
    int b = blockIdx.x, tid = threadIdx.x;
    if (b < nInterp) {
        int cx = b % cxB, n = b / cxB;
        int c = cx * 256 + tid;
        int i0 = idx3[n * 3], i1 = idx3[n * 3 + 1], i2 = idx3[n * 3 + 2];
        float w0 = w3[n * 3], w1 = w3[n * 3 + 1], w2 = w3[n * 3 + 2];
        float f0 = bf2f(fcT[(size_t)i0 * Cc + c]);
        float f1 = bf2f(fcT[(size_t)i1 * Cc + c]);
        float f2_ = bf2f(fcT[(size_t)i2 * Cc + c]);
        float v = fmaf(w2, f2_, fmaf(w1, f1, w0 * f0));
        xbuf[(size_t)n * Cin + c] = f2bf(v);
    } else {
        int b2 = b - nInterp;
        int nb = b2 % Nb, cb = b2 / Nb;
        int n0 = nb * 64, c0 = cb * 64;
        int tx = tid & 63, ty = tid >> 6;
#pragma unroll
        for (int i = 0; i < 16; ++i)
            t[ty + 4 * i][tx] = ff[(size_t)(c0 + ty + 4 * i) * N + n0 + tx];
        __syncthreads();
#pragma unroll
        for (int i = 0; i < 16; ++i)
            xbuf[(size_t)(n0 + ty + 4 * i) * Cin + Cc + c0 + tx] = f2bf(t[tx][ty + 4 * i]);
    }
}

// ---------- bf16 MFMA GEMM -> bf16 D [O][N] + per-block channel (sum,sumsq) partials ----------
#define BK 32
__global__ __launch_bounds__(256) void gemm_bf16_kernel(
    const unsigned short* __restrict__ A,  // [O][K] bf16
    const unsigned short* __restrict__ B,  // [Ntot][K] bf16
    unsigned short* __restrict__ Dh,       // [O][Ntot] bf16 (pre-BN activations)
    float* __restrict__ psumG,             // [Ntot/128][O]
    float* __restrict__ psqG,              // [Ntot/128][O]
    int K, int Ntot, int O) {
    __shared__ short As[128 * BK], Bs[128 * BK];
    int tid = threadIdx.x;
    int lane = tid & 63, wid = tid >> 6;
    int wm = wid & 1, wn = wid >> 1;
    int o0 = blockIdx.y * 128, n0 = blockIdx.x * 128;
    int r16 = lane & 15, kg = lane >> 4;
    float4v acc[4][4];
#pragma unroll
    for (int a = 0; a < 4; ++a)
#pragma unroll
        for (int b = 0; b < 4; ++b)
            acc[a][b] = (float4v){0.f, 0.f, 0.f, 0.f};
    for (int k0 = 0; k0 < K; k0 += BK) {
#pragma unroll
        for (int h = 0; h < 2; ++h) {
            int ch = tid + h * 256;
            int row = ch >> 2, kq = ch & 3;
            __builtin_amdgcn_global_load_lds(
                (const __attribute__((address_space(1))) void*)(A + (size_t)(o0 + row) * K + k0 + kq * 8),
                (__attribute__((address_space(3))) void*)&As[ch * 8], 16, 0, 0);
            __builtin_amdgcn_global_load_lds(
                (const __attribute__((address_space(1))) void*)(B + (size_t)(n0 + row) * K + k0 + kq * 8),
                (__attribute__((address_space(3))) void*)&Bs[ch * 8], 16, 0, 0);
        }
        __syncthreads();
        short8 af[4], bfr[4];
#pragma unroll
        for (int mi = 0; mi < 4; ++mi)
            af[mi] = *(const short8*)(const void*)&As[(wm * 64 + mi * 16 + r16) * BK + kg * 8];
#pragma unroll
        for (int ni = 0; ni < 4; ++ni)
            bfr[ni] = *(const short8*)(const void*)&Bs[(wn * 64 + ni * 16 + r16) * BK + kg * 8];
#pragma unroll
        for (int mi = 0; mi < 4; ++mi)
#pragma unroll
            for (int ni = 0; ni < 4; ++ni)
                acc[mi][ni] = __builtin_amdgcn_mfma_f32_16x16x32_bf16(af[mi], bfr[ni], acc[mi][ni], 0, 0, 0);
        __syncthreads();
    }
    // bf16 D write (stats below stay f32 from acc)
#pragma unroll
    for (int mi = 0; mi < 4; ++mi) {
        int obase = o0 + wm * 64 + mi * 16 + kg * 4;
#pragma unroll
        for (int ni = 0; ni < 4; ++ni) {
            int col = n0 + wn * 64 + ni * 16 + r16;
#pragma unroll
            for (int r = 0; r < 4; ++r)
                Dh[(size_t)(obase + r) * Ntot + col] = f2bf(acc[mi][ni][r]);
        }
    }
    // per-channel partials over this block's 128 cols (deterministic fixed-order)
    float2* red = (float2*)As;
#pragma unroll
    for (int mi = 0; mi < 4; ++mi) {
#pragma unroll
        for (int r = 0; r < 4; ++r) {
            float s = 0.f, q = 0.f;
#pragma unroll
            for (int ni = 0; ni < 4; ++ni) {
                float v = acc[mi][ni][r];
                s += v; q += v * v;
            }
#pragma unroll
            for (int off = 1; off <= 8; off <<= 1) {
                s += __shfl_xor(s, off);
                q += __shfl_xor(q, off);
            }
            if (r16 == 0) {
                int row = wm * 64 + mi * 16 + kg * 4 + r;
                red[row * 2 + wn] = make_float2(s, q);
            }
        }
    }
    __syncthreads();
    if (tid < 128) {
        float2 a = red[tid * 2 + 0], b = red[tid * 2 + 1];
        int o = o0 + tid;
        psumG[(size_t)blockIdx.x * O + o] = a.x + b.x;
        psqG [(size_t)blockIdx.x * O + o] = a.y + b.y;
    }
}

// ---------- layer1 apply: stats-reduce + BN + ReLU + transpose bf16 [O][N] -> [N][C] ----------
__global__ __launch_bounds__(256) void bnrelu_tr_kernel(
    const unsigned short* __restrict__ Dh, const float* __restrict__ psumG, const float* __restrict__ psqG,
    const float* __restrict__ g, const float* __restrict__ b,
    unsigned short* __restrict__ Z, int Nn, int C, int NB) {
    __shared__ float t[64][65];
    __shared__ float2 st[4][64];
    __shared__ float2 msr[64];
    int tid = threadIdx.x;
    int tx = tid & 63, ty = tid >> 6;
    int n0 = blockIdx.x * 64, o0 = blockIdx.y * 64;
    {
        int ch = tid & 63, q4 = tid >> 6;
        float s = 0.f, qq = 0.f;
        int per = NB / 4;
        for (int i = 0; i < per; ++i) {
            int bx = q4 * per + i;
            s  += psumG[(size_t)bx * C + o0 + ch];
            qq += psqG [(size_t)bx * C + o0 + ch];
        }
        st[q4][ch] = make_float2(s, qq);
    }
#pragma unroll
    for (int i = 0; i < 16; ++i)
        t[ty + 4 * i][tx] = bf2f(Dh[(size_t)(o0 + ty + 4 * i) * Nn + n0 + tx]);
    __syncthreads();
    if (tid < 64) {
        float2 a = st[0][tid], b2 = st[1][tid], c2 = st[2][tid], d2 = st[3][tid];
        float S = (a.x + b2.x) + (c2.x + d2.x);
        float Q = (a.y + b2.y) + (c2.y + d2.y);
        float m = S / Nn;
        float v = Q / Nn - m * m;
        msr[tid] = make_float2(m, rsqrtf(v + 1e-5f));
    }
    __syncthreads();
    int o = o0 + tx;
    float mm = msr[tx].x, rr = msr[tx].y, gg = g[o], bb = b[o];
#pragma unroll
    for (int i = 0; i < 16; ++i) {
        float v = t[tx][ty + 4 * i];
        v = gg * (v - mm) * rr + bb;
        v = fmaxf(v, 0.f);
        Z[(size_t)(n0 + ty + 4 * i) * C + o] = f2bf(v);
    }
}

// ---------- layer2 apply: stats-reduce + BN + ReLU; bf16 D -> f32 out ----------
__global__ __launch_bounds__(256) void bnrelu2_kernel(
    const unsigned short* __restrict__ Dh, float* __restrict__ Y,
    const float* __restrict__ psumG, const float* __restrict__ psqG,
    const float* __restrict__ g, const float* __restrict__ b, int Nn, int C, int NB) {
    __shared__ float2 red[128];
    __shared__ float2 ms;
    int c = blockIdx.y, tid = threadIdx.x;
    if (tid < NB)
        red[tid] = make_float2(psumG[(size_t)tid * C + c], psqG[(size_t)tid * C + c]);
    __syncthreads();
    for (int s2 = NB / 2; s2 > 0; s2 >>= 1) {
        if (tid < s2) {
            red[tid].x += red[tid + s2].x;
            red[tid].y += red[tid + s2].y;
        }
        __syncthreads();
    }
    if (tid == 0) {
        float m = red[0].x / Nn;
        ms = make_float2(m, rsqrtf(red[0].y / Nn - m * m + 1e-5f));
    }
    __syncthreads();
    float mm = ms.x, rr = ms.y, gg = g[c], bb = b[c];
    int q = (int)blockIdx.x * 256 + tid;           // quad index within channel
    ushort4 dv = ((const ushort4*)(Dh + (size_t)c * Nn))[q];
    float4 v;
    v.x = fmaxf(gg * (bf2f(dv.x) - mm) * rr + bb, 0.f);
    v.y = fmaxf(gg * (bf2f(dv.y) - mm) * rr + bb, 0.f);
    v.z = fmaxf(gg * (bf2f(dv.z) - mm) * rr + bb, 0.f);
    v.w = fmaxf(gg * (bf2f(dv.w) - mm) * rr + bb, 0.f);
    ((float4*)Y)[(size_t)c * (Nn >> 2) + q] = v;
}

extern "C" void kernel_launch(void* const* d_in, const int* in_sizes, int n_in,
                              void* d_out, int out_size, void* d_ws, size_t ws_size,
                              hipStream_t stream) {
    const float* xyzf = (const float*)d_in[0];
    const float* xyzc = (const float*)d_in[1];
    const float* ff   = (const float*)d_in[2];
    const float* fc   = (const float*)d_in[3];
    const float* W1   = (const float*)d_in[4];
    const float* g1   = (const float*)d_in[5];
    const float* b1   = (const float*)d_in[6];
    const float* W2   = (const float*)d_in[7];
    const float* g2   = (const float*)d_in[8];
    const float* b2   = (const float*)d_in[9];

    int N  = in_sizes[0] / 3;       // 16384
    int M  = in_sizes[1] / 3;       // 4096
    int Cf = in_sizes[2] / N;       // 256
    int Cc = in_sizes[3] / M;       // 512
    int h1 = in_sizes[5];           // 512
    int h2 = in_sizes[8];           // 512
    int Cin = Cc + Cf;              // 768
    float* out = (float*)d_out;

    // workspace carve (~48 MB)
    char* p = (char*)d_ws;
    unsigned short* W1h = (unsigned short*)p; p += (size_t)h1 * Cin * 2;
    unsigned short* W2h = (unsigned short*)p; p += (size_t)h2 * h1 * 2;
    unsigned short* fcT = (unsigned short*)p; p += (size_t)M * Cc * 2;
    int*   idx3 = (int*)p;   p += (size_t)N * 3 * sizeof(int);
    float* w3   = (float*)p; p += (size_t)N * 3 * sizeof(float);
    float4* cand4 = (float4*)p; p += (size_t)M * sizeof(float4);
    int NB = N / 128;                                   // 128 GEMM n-blocks
    float* psumG = (float*)p; p += (size_t)NB * h1 * sizeof(float);
    float* psqG  = (float*)p; p += (size_t)NB * h1 * sizeof(float);
    unsigned short* d1h = (unsigned short*)p; p += (size_t)h1 * N * 2;   // bf16 pre-BN D, both layers
    unsigned short* xbuf = (unsigned short*)p; p += (size_t)N * Cin * 2;
    // aliases inside xbuf (dead before xbuf is first written):
    float* candd = (float*)xbuf;                        // [KCH*3][N]
    int*   candi = (int*)((char*)xbuf + (size_t)KCH * 3 * N * sizeof(float));
    unsigned short* y2 = xbuf;                          // [N][h1] bf16, alias after GEMM1

    // 1. prologue
    int nW1 = h1 * Cin / 1024, nW2 = h2 * h1 / 1024;
    int Mb = M / 64, nTR = Mb * (Cc / 64), nPR = (M + 255) / 256;
    prologue_kernel<<<nW1 + nW2 + nTR + nPR, 256, 0, stream>>>(
        W1, W2, W1h, W2h, fc, fcT, xyzc, cand4, M, Cc, nW1, nW2, nTR, Mb);

    // 2-3. kNN
    knn_scan_kernel<<<dim3(N / 256, KCH), 256, 0, stream>>>(xyzf, cand4, N, M, candd, candi);
    knn_merge_kernel<<<N / 256, 256, 0, stream>>>(candd, candi, xyzf, xyzc, N, M, idx3, w3);

    // 4. build x
    int cxB = Cc / 256, nInterp = cxB * N, Nb = N / 64, nTF = Nb * (Cf / 64);
    build_x_kernel<<<nInterp + nTF, 256, 0, stream>>>(
        fcT, idx3, w3, ff, xbuf, N, Cin, Cc, nInterp, cxB, Nb);

    // 5-6. layer 1
    gemm_bf16_kernel<<<dim3(N / 128, h1 / 128), 256, 0, stream>>>(
        W1h, xbuf, d1h, psumG, psqG, Cin, N, h1);
    bnrelu_tr_kernel<<<dim3(N / 64, h1 / 64), 256, 0, stream>>>(
        d1h, psumG, psqG, g1, b1, y2, N, h1, NB);

    // 7-8. layer 2
    gemm_bf16_kernel<<<dim3(N / 128, h2 / 128), 256, 0, stream>>>(
        W2h, y2, d1h, psumG, psqG, h1, N, h2);
    bnrelu2_kernel<<<dim3(N / 1024, h2), 256, 0, stream>>>(
        d1h, out, psumG, psqG, g2, b2, N, h2, NB);
}